// Round 1
// baseline (1147.166 us; speedup 1.0000x reference)
//
#include <hip/hip_runtime.h>
#include <hip/hip_bf16.h>
#include <cstddef>

#define GN 50000
#define GE 800000
#define GH 4
#define GD 32
#define SLOPE 0.2f

// ---------------- CSR build ----------------
__global__ void k_hist(const int* __restrict__ dst, int* __restrict__ deg, int E) {
    int i = blockIdx.x * 256 + threadIdx.x;
    if (i < E) atomicAdd(&deg[dst[i]], 1);
}

__global__ void k_scan1(const int* __restrict__ deg, int* __restrict__ row_ptr,
                        int* __restrict__ partials, int n) {
    __shared__ int s[256];
    int t = threadIdx.x;
    int i = blockIdx.x * 256 + t;
    int v = (i < n) ? deg[i] : 0;
    s[t] = v;
    __syncthreads();
    for (int off = 1; off < 256; off <<= 1) {
        int add = (t >= off) ? s[t - off] : 0;
        __syncthreads();
        s[t] += add;
        __syncthreads();
    }
    if (i < n) row_ptr[i] = s[t] - v;          // exclusive within chunk
    if (t == 255) partials[blockIdx.x] = s[255];
}

__global__ void k_scan2(int* __restrict__ partials, int nb) {
    __shared__ int s[256];
    int t = threadIdx.x;
    int v = (t < nb) ? partials[t] : 0;
    s[t] = v;
    __syncthreads();
    for (int off = 1; off < 256; off <<= 1) {
        int add = (t >= off) ? s[t - off] : 0;
        __syncthreads();
        s[t] += add;
        __syncthreads();
    }
    if (t < nb) partials[t] = s[t] - v;        // exclusive chunk offsets
}

__global__ void k_scan3(int* __restrict__ row_ptr, int* __restrict__ wpos,
                        const int* __restrict__ partials, int n, int E) {
    int i = blockIdx.x * 256 + threadIdx.x;
    if (i < n) {
        int rp = row_ptr[i] + partials[i >> 8];
        row_ptr[i] = rp;
        wpos[i] = rp;
        if (i == 0) row_ptr[n] = E;
    }
}

__global__ void k_fill(const int* __restrict__ src, const int* __restrict__ dst,
                       int* __restrict__ wpos, int* __restrict__ csr_src, int E) {
    int i = blockIdx.x * 256 + threadIdx.x;
    if (i < E) {
        int p = atomicAdd(&wpos[dst[i]], 1);
        csr_src[p] = src[i];
    }
}

// ---------------- GEMM: C[M,128] = A[M,128] @ B[128,128] ----------------
__global__ __launch_bounds__(256) void gemm_nk128(const float* __restrict__ A,
                                                  const float* __restrict__ B,
                                                  float* __restrict__ C, int M) {
    __shared__ float As[64][128];
    int row0 = blockIdx.x * 64;
    int tid = threadIdx.x;
    // stage A tile (64x128 floats) via float4
    for (int i = tid; i < 64 * 32; i += 256) {
        int r = i >> 5;
        int c = (i & 31) << 2;
        int gr = row0 + r;
        float4 v = make_float4(0.f, 0.f, 0.f, 0.f);
        if (gr < M) v = *(const float4*)&A[(size_t)gr * 128 + c];
        *(float4*)&As[r][c] = v;
    }
    __syncthreads();
    int tx = tid & 31, ty = tid >> 5;   // tx: col group (4 cols), ty: row group (8 rows)
    int c0 = tx << 2;
    float acc[8][4];
#pragma unroll
    for (int j = 0; j < 8; j++)
#pragma unroll
        for (int c = 0; c < 4; c++) acc[j][c] = 0.f;

    for (int k = 0; k < 128; k += 4) {
        float4 b0 = *(const float4*)&B[(k + 0) * 128 + c0];
        float4 b1 = *(const float4*)&B[(k + 1) * 128 + c0];
        float4 b2 = *(const float4*)&B[(k + 2) * 128 + c0];
        float4 b3 = *(const float4*)&B[(k + 3) * 128 + c0];
#pragma unroll
        for (int j = 0; j < 8; j++) {
            float4 a = *(const float4*)&As[ty * 8 + j][k];
            acc[j][0] += a.x * b0.x + a.y * b1.x + a.z * b2.x + a.w * b3.x;
            acc[j][1] += a.x * b0.y + a.y * b1.y + a.z * b2.y + a.w * b3.y;
            acc[j][2] += a.x * b0.z + a.y * b1.z + a.z * b2.z + a.w * b3.z;
            acc[j][3] += a.x * b0.w + a.y * b1.w + a.z * b2.w + a.w * b3.w;
        }
    }
#pragma unroll
    for (int j = 0; j < 8; j++) {
        int gr = row0 + ty * 8 + j;
        if (gr < M) {
            float4 v = make_float4(acc[j][0], acc[j][1], acc[j][2], acc[j][3]);
            *(float4*)&C[(size_t)gr * 128 + c0] = v;
        }
    }
}

// ---------------- attention logits el/er ----------------
__global__ void compute_lr(const float* __restrict__ feat, const float* __restrict__ al,
                           const float* __restrict__ ar, float* __restrict__ el,
                           float* __restrict__ er, int NH) {
    int i = blockIdx.x * 256 + threadIdx.x;   // i = n*H + h
    if (i >= NH) return;
    int h = i & (GH - 1);
    const float* f = feat + (size_t)(i >> 2) * 128 + h * GD;
    const float* a = al + h * GD;
    const float* b = ar + h * GD;
    float sl = 0.f, sr = 0.f;
#pragma unroll
    for (int d = 0; d < GD; d += 4) {
        float4 fv = *(const float4*)&f[d];
        float4 av = *(const float4*)&a[d];
        float4 bv = *(const float4*)&b[d];
        sl += fv.x * av.x + fv.y * av.y + fv.z * av.z + fv.w * av.w;
        sr += fv.x * bv.x + fv.y * bv.y + fv.z * bv.z + fv.w * bv.w;
    }
    el[i] = sl;
    er[i] = sr;
}

// ---------------- edge-softmax + aggregate (+residual, +elu, +mixup) ----------------
// one 32-lane half-wave per (node, head); lane = feature dim d
__global__ __launch_bounds__(256) void gat_agg(
    const float* __restrict__ feat, const float* __restrict__ el,
    const float* __restrict__ er, const int* __restrict__ row_ptr,
    const int* __restrict__ csr_src, const float* __restrict__ resid,
    const float* __restrict__ mixh, const float* __restrict__ lamb,
    float* __restrict__ out, int NH) {
    int pair = blockIdx.x * 8 + (threadIdx.x >> 5);
    if (pair >= NH) return;
    int lane = threadIdx.x & 31;
    int n = pair >> 2, h = pair & 3;
    int base = row_ptr[n], end = row_ptr[n + 1];
    int deg = end - base;
    float ern = er[pair];

    // pass 1: max over incoming edges (parallel over lanes)
    float m = -1e30f;
    for (int i = lane; i < deg; i += 32) {
        int s = csr_src[base + i];
        float e = el[s * GH + h] + ern;
        e = e > 0.f ? e : SLOPE * e;
        m = fmaxf(m, e);
    }
#pragma unroll
    for (int off = 16; off; off >>= 1) m = fmaxf(m, __shfl_xor(m, off, 32));

    // pass 2: exp-sum + weighted feature gather (lane owns dim d)
    float acc = 0.f, ssum = 0.f;
    const float* fcol = feat + h * GD + lane;
    for (int i = 0; i < deg; i++) {
        int s = csr_src[base + i];
        float e = el[s * GH + h] + ern;
        e = e > 0.f ? e : SLOPE * e;
        float w = __expf(e - m);
        ssum += w;
        acc += w * fcol[(size_t)s * 128];
    }
    float v = (deg > 0) ? acc / ssum : 0.f;
    int idx = n * 128 + h * GD + lane;
    if (resid) v += resid[idx];
    v = v > 0.f ? v : __expf(v) - 1.f;   // elu
    if (mixh) {
        float lam = lamb[0];
        v = lam * mixh[idx] + (1.f - lam) * v;
    }
    out[idx] = v;
}

// ---------------- output projection: logits = h @ Wout + bout ----------------
__global__ __launch_bounds__(256) void gemm_out(const float* __restrict__ A,
                                                const float* __restrict__ W,
                                                const float* __restrict__ bias,
                                                float* __restrict__ C, int M) {
    int n = blockIdx.x * 4 + (threadIdx.x >> 6);
    int lane = threadIdx.x & 63;
    if (n >= M || lane >= 40) return;
    const float* a = A + (size_t)n * 128;
    float acc = bias[lane];
#pragma unroll 8
    for (int k = 0; k < 128; k += 4) {
        float4 av = *(const float4*)&a[k];
        acc += av.x * W[(k + 0) * 40 + lane] + av.y * W[(k + 1) * 40 + lane] +
               av.z * W[(k + 2) * 40 + lane] + av.w * W[(k + 3) * 40 + lane];
    }
    C[(size_t)n * 40 + lane] = acc;
}

extern "C" void kernel_launch(void* const* d_in, const int* in_sizes, int n_in,
                              void* d_out, int out_size, void* d_ws, size_t ws_size,
                              hipStream_t stream) {
    const float* inputs = (const float*)d_in[0];
    const float* target = (const float*)d_in[1];
    const float* lamb   = (const float*)d_in[2];
    const float* W0     = (const float*)d_in[3];
    const float* al0    = (const float*)d_in[4];
    const float* ar0    = (const float*)d_in[5];
    const float* W1     = (const float*)d_in[6];
    const float* al1    = (const float*)d_in[7];
    const float* ar1    = (const float*)d_in[8];
    const float* Wout   = (const float*)d_in[9];
    const float* bout   = (const float*)d_in[10];
    const int*   src    = (const int*)d_in[11];
    const int*   dst    = (const int*)d_in[12];

    float* out = (float*)d_out;
    float* outh = out;                          // [N,128]
    float* outlog = out + (size_t)GN * 128;     // [N,40]

    // workspace layout
    float* feat = (float*)d_ws;                       // N*128
    float* t0   = feat + (size_t)GN * 128;            // N*128
    float* el   = t0 + (size_t)GN * 128;              // N*H
    float* er   = el + (size_t)GN * GH;               // N*H
    int* row_ptr  = (int*)(er + (size_t)GN * GH);     // N+1
    int* wpos     = row_ptr + (GN + 1);               // N
    int* csr_src  = wpos + GN;                        // E
    int* partials = csr_src + GE;                     // 256

    const int NH = GN * GH;
    const int nb = (GN + 255) / 256;          // scan chunks (196)
    const int eb = (GE + 255) / 256;
    const int gblocks = (GN + 63) / 64;
    const int lrblocks = (NH + 255) / 256;
    const int aggblocks = (NH + 7) / 8;

    // ---- CSR build (graph identical every call; ws is re-poisoned, so rebuild) ----
    hipMemsetAsync(wpos, 0, GN * sizeof(int), stream);
    k_hist<<<eb, 256, 0, stream>>>(dst, wpos, GE);
    k_scan1<<<nb, 256, 0, stream>>>(wpos, row_ptr, partials, GN);
    k_scan2<<<1, 256, 0, stream>>>(partials, nb);
    k_scan3<<<nb, 256, 0, stream>>>(row_ptr, wpos, partials, GN, GE);
    k_fill<<<eb, 256, 0, stream>>>(src, dst, wpos, csr_src, GE);

    // ---- path 1 (inputs) -> h1 stored directly in outh ----
    gemm_nk128<<<gblocks, 256, 0, stream>>>(inputs, W0, feat, GN);
    compute_lr<<<lrblocks, 256, 0, stream>>>(feat, al0, ar0, el, er, NH);
    gat_agg<<<aggblocks, 256, 0, stream>>>(feat, el, er, row_ptr, csr_src,
                                           nullptr, nullptr, nullptr, t0, NH);
    gemm_nk128<<<gblocks, 256, 0, stream>>>(t0, W1, feat, GN);
    compute_lr<<<lrblocks, 256, 0, stream>>>(feat, al1, ar1, el, er, NH);
    gat_agg<<<aggblocks, 256, 0, stream>>>(feat, el, er, row_ptr, csr_src,
                                           t0, nullptr, nullptr, outh, NH);

    // ---- path 2 (target), final agg fuses mixup: outh = lam*outh + (1-lam)*h2 ----
    gemm_nk128<<<gblocks, 256, 0, stream>>>(target, W0, feat, GN);
    compute_lr<<<lrblocks, 256, 0, stream>>>(feat, al0, ar0, el, er, NH);
    gat_agg<<<aggblocks, 256, 0, stream>>>(feat, el, er, row_ptr, csr_src,
                                           nullptr, nullptr, nullptr, t0, NH);
    gemm_nk128<<<gblocks, 256, 0, stream>>>(t0, W1, feat, GN);
    compute_lr<<<lrblocks, 256, 0, stream>>>(feat, al1, ar1, el, er, NH);
    gat_agg<<<aggblocks, 256, 0, stream>>>(feat, el, er, row_ptr, csr_src,
                                           t0, outh, lamb, outh, NH);

    // ---- logits ----
    gemm_out<<<(GN + 3) / 4, 256, 0, stream>>>(outh, Wout, bout, outlog, GN);
}

// Round 2
// 569.231 us; speedup vs baseline: 2.0153x; 2.0153x over previous
//
#include <hip/hip_runtime.h>
#include <hip/hip_bf16.h>
#include <cstddef>

#define GN 50000
#define GE 800000
#define GH 4
#define GD 32
#define SLOPE 0.2f

typedef unsigned short ushort_t;
typedef unsigned int uint_t;

__device__ __forceinline__ ushort_t f2bf(float f) {
    union { float f; uint_t u; } v; v.f = f;
    uint_t r = v.u + 0x7fff + ((v.u >> 16) & 1);   // RNE
    return (ushort_t)(r >> 16);
}

// ---------------- CSR build ----------------
__global__ void k_hist(const int* __restrict__ dst, int* __restrict__ deg, int E) {
    int i = blockIdx.x * 256 + threadIdx.x;
    if (i < E) atomicAdd(&deg[dst[i]], 1);
}

__global__ void k_scan1(const int* __restrict__ deg, int* __restrict__ row_ptr,
                        int* __restrict__ partials, int n) {
    __shared__ int s[256];
    int t = threadIdx.x;
    int i = blockIdx.x * 256 + t;
    int v = (i < n) ? deg[i] : 0;
    s[t] = v;
    __syncthreads();
    for (int off = 1; off < 256; off <<= 1) {
        int add = (t >= off) ? s[t - off] : 0;
        __syncthreads();
        s[t] += add;
        __syncthreads();
    }
    if (i < n) row_ptr[i] = s[t] - v;
    if (t == 255) partials[blockIdx.x] = s[255];
}

__global__ void k_scan2(int* __restrict__ partials, int nb) {
    __shared__ int s[256];
    int t = threadIdx.x;
    int v = (t < nb) ? partials[t] : 0;
    s[t] = v;
    __syncthreads();
    for (int off = 1; off < 256; off <<= 1) {
        int add = (t >= off) ? s[t - off] : 0;
        __syncthreads();
        s[t] += add;
        __syncthreads();
    }
    if (t < nb) partials[t] = s[t] - v;
}

__global__ void k_scan3(int* __restrict__ row_ptr, int* __restrict__ wpos,
                        const int* __restrict__ partials, int n, int E) {
    int i = blockIdx.x * 256 + threadIdx.x;
    if (i < n) {
        int rp = row_ptr[i] + partials[i >> 8];
        row_ptr[i] = rp;
        wpos[i] = rp;
        if (i == 0) row_ptr[n] = E;
    }
}

__global__ void k_fill(const int* __restrict__ src, const int* __restrict__ dst,
                       int* __restrict__ wpos, int* __restrict__ csr_src, int E) {
    int i = blockIdx.x * 256 + threadIdx.x;
    if (i < E) {
        int p = atomicAdd(&wpos[dst[i]], 1);
        csr_src[p] = src[i];
    }
}

// ---------------- GEMM: featb[M,128](bf16) = A[M,128] @ B[128,128] ----------------
// A rows < GN come from A0, rows >= GN from A1 (A1 may equal A0+GN*128 slice)
__global__ __launch_bounds__(256) void gemm_nk128(const float* __restrict__ A0,
                                                  const float* __restrict__ A1,
                                                  const float* __restrict__ B,
                                                  ushort_t* __restrict__ featb, int M) {
    __shared__ float As[64][128];
    int row0 = blockIdx.x * 64;
    int tid = threadIdx.x;
    for (int i = tid; i < 64 * 32; i += 256) {
        int r = i >> 5;
        int c = (i & 31) << 2;
        int gr = row0 + r;
        float4 v = make_float4(0.f, 0.f, 0.f, 0.f);
        if (gr < M) {
            const float* Ar = (gr < GN) ? (A0 + (size_t)gr * 128)
                                        : (A1 + (size_t)(gr - GN) * 128);
            v = *(const float4*)&Ar[c];
        }
        *(float4*)&As[r][c] = v;
    }
    __syncthreads();
    int tx = tid & 31, ty = tid >> 5;
    int c0 = tx << 2;
    float acc[8][4];
#pragma unroll
    for (int j = 0; j < 8; j++)
#pragma unroll
        for (int c = 0; c < 4; c++) acc[j][c] = 0.f;

    for (int k = 0; k < 128; k += 4) {
        float4 b0 = *(const float4*)&B[(k + 0) * 128 + c0];
        float4 b1 = *(const float4*)&B[(k + 1) * 128 + c0];
        float4 b2 = *(const float4*)&B[(k + 2) * 128 + c0];
        float4 b3 = *(const float4*)&B[(k + 3) * 128 + c0];
#pragma unroll
        for (int j = 0; j < 8; j++) {
            float4 a = *(const float4*)&As[ty * 8 + j][k];
            acc[j][0] += a.x * b0.x + a.y * b1.x + a.z * b2.x + a.w * b3.x;
            acc[j][1] += a.x * b0.y + a.y * b1.y + a.z * b2.y + a.w * b3.y;
            acc[j][2] += a.x * b0.z + a.y * b1.z + a.z * b2.z + a.w * b3.z;
            acc[j][3] += a.x * b0.w + a.y * b1.w + a.z * b2.w + a.w * b3.w;
        }
    }
#pragma unroll
    for (int j = 0; j < 8; j++) {
        int gr = row0 + ty * 8 + j;
        if (gr < M) {
            ushort4 o;
            o.x = f2bf(acc[j][0]);
            o.y = f2bf(acc[j][1]);
            o.z = f2bf(acc[j][2]);
            o.w = f2bf(acc[j][3]);
            *(ushort4*)&featb[(size_t)gr * 128 + c0] = o;
        }
    }
}

// ---------------- attention logits el/er (bf16 feat) ----------------
__global__ void compute_lr(const ushort_t* __restrict__ featb,
                           const float* __restrict__ al, const float* __restrict__ ar,
                           float* __restrict__ el, float* __restrict__ er, int NPH) {
    int i = blockIdx.x * 256 + threadIdx.x;   // i = p*H + h
    if (i >= NPH) return;
    int h = i & (GH - 1);
    const uint_t* f = (const uint_t*)(featb + (size_t)(i >> 2) * 128 + h * GD);
    const float* a = al + h * GD;
    const float* b = ar + h * GD;
    float sl = 0.f, sr = 0.f;
#pragma unroll
    for (int q = 0; q < 16; q++) {
        uint_t u = f[q];
        float x = __uint_as_float(u << 16);
        float y = __uint_as_float(u & 0xffff0000u);
        sl += x * a[2 * q] + y * a[2 * q + 1];
        sr += x * b[2 * q] + y * b[2 * q + 1];
    }
    el[i] = sl;
    er[i] = sr;
}

// ---------------- edge-softmax + aggregate, all heads fused ----------------
// one 64-lane wave per (node,path) row p in [0,2N); lane owns dims 2l,2l+1; head=l>>4
// No max-subtraction: |e| <= ~2 here, exp is safe and math-identical.
__global__ __launch_bounds__(256) void gat_agg(
    const ushort_t* __restrict__ featb, const float* __restrict__ el,
    const float* __restrict__ er, const int* __restrict__ row_ptr,
    const int* __restrict__ csr_src, float* __restrict__ io,
    int use_resid, int NP) {
    int p = blockIdx.x * 4 + (threadIdx.x >> 6);
    if (p >= NP) return;
    int lane = threadIdx.x & 63;
    int hh = lane >> 4;
    int n = (p < GN) ? p : p - GN;
    int off = (p < GN) ? 0 : GN;
    int base = row_ptr[n];
    int deg = row_ptr[n + 1] - base;
    float ern = er[p * 4 + hh];

    float acc0 = 0.f, acc1 = 0.f, ssum = 0.f;
    int i = 0;
    for (; i + 4 <= deg; i += 4) {
        int s0 = csr_src[base + i + 0] + off;
        int s1 = csr_src[base + i + 1] + off;
        int s2 = csr_src[base + i + 2] + off;
        int s3 = csr_src[base + i + 3] + off;
        float e0 = el[s0 * 4 + hh] + ern;
        float e1 = el[s1 * 4 + hh] + ern;
        float e2 = el[s2 * 4 + hh] + ern;
        float e3 = el[s3 * 4 + hh] + ern;
        uint_t f0 = *(const uint_t*)&featb[(size_t)s0 * 128 + (lane << 1)];
        uint_t f1 = *(const uint_t*)&featb[(size_t)s1 * 128 + (lane << 1)];
        uint_t f2 = *(const uint_t*)&featb[(size_t)s2 * 128 + (lane << 1)];
        uint_t f3 = *(const uint_t*)&featb[(size_t)s3 * 128 + (lane << 1)];
        e0 = e0 > 0.f ? e0 : SLOPE * e0;
        e1 = e1 > 0.f ? e1 : SLOPE * e1;
        e2 = e2 > 0.f ? e2 : SLOPE * e2;
        e3 = e3 > 0.f ? e3 : SLOPE * e3;
        float w0 = __expf(e0), w1 = __expf(e1), w2 = __expf(e2), w3 = __expf(e3);
        ssum += (w0 + w1) + (w2 + w3);
        acc0 += w0 * __uint_as_float(f0 << 16) + w1 * __uint_as_float(f1 << 16) +
                w2 * __uint_as_float(f2 << 16) + w3 * __uint_as_float(f3 << 16);
        acc1 += w0 * __uint_as_float(f0 & 0xffff0000u) + w1 * __uint_as_float(f1 & 0xffff0000u) +
                w2 * __uint_as_float(f2 & 0xffff0000u) + w3 * __uint_as_float(f3 & 0xffff0000u);
    }
    for (; i < deg; i++) {
        int s = csr_src[base + i] + off;
        float e = el[s * 4 + hh] + ern;
        uint_t f = *(const uint_t*)&featb[(size_t)s * 128 + (lane << 1)];
        e = e > 0.f ? e : SLOPE * e;
        float w = __expf(e);
        ssum += w;
        acc0 += w * __uint_as_float(f << 16);
        acc1 += w * __uint_as_float(f & 0xffff0000u);
    }
    float inv = (deg > 0) ? 1.f / ssum : 0.f;
    float v0 = acc0 * inv, v1 = acc1 * inv;
    size_t idx = (size_t)p * 128 + (lane << 1);
    if (use_resid) {
        float2 r = *(const float2*)&io[idx];
        v0 += r.x;
        v1 += r.y;
    }
    v0 = v0 > 0.f ? v0 : __expf(v0) - 1.f;
    v1 = v1 > 0.f ? v1 : __expf(v1) - 1.f;
    *(float2*)&io[idx] = make_float2(v0, v1);
}

// ---------------- mixup + output projection ----------------
// hm = lam*h1 + (1-lam)*h2 ; outh = hm ; logits = hm @ Wout + bout
__global__ __launch_bounds__(256) void out_mix(const float* __restrict__ hbuf,
                                               const float* __restrict__ Wout,
                                               const float* __restrict__ bout,
                                               const float* __restrict__ lamb,
                                               float* __restrict__ outh,
                                               float* __restrict__ outlog, int Nn) {
    __shared__ float hs[4][128];
    int w = threadIdx.x >> 6;
    int node = blockIdx.x * 4 + w;
    int lane = threadIdx.x & 63;
    float lam = lamb[0];
    if (node < Nn) {
        size_t i1 = (size_t)node * 128 + (lane << 1);
        size_t i2 = (size_t)(node + GN) * 128 + (lane << 1);
        float2 a = *(const float2*)&hbuf[i1];
        float2 b = *(const float2*)&hbuf[i2];
        float m0 = lam * a.x + (1.f - lam) * b.x;
        float m1 = lam * a.y + (1.f - lam) * b.y;
        *(float2*)&outh[i1] = make_float2(m0, m1);
        hs[w][lane * 2] = m0;
        hs[w][lane * 2 + 1] = m1;
    }
    __syncthreads();
    if (node < Nn && lane < 40) {
        float acc = bout[lane];
#pragma unroll 4
        for (int k = 0; k < 128; k++) acc += hs[w][k] * Wout[k * 40 + lane];
        outlog[(size_t)node * 40 + lane] = acc;
    }
}

extern "C" void kernel_launch(void* const* d_in, const int* in_sizes, int n_in,
                              void* d_out, int out_size, void* d_ws, size_t ws_size,
                              hipStream_t stream) {
    const float* inputs = (const float*)d_in[0];
    const float* target = (const float*)d_in[1];
    const float* lamb   = (const float*)d_in[2];
    const float* W0     = (const float*)d_in[3];
    const float* al0    = (const float*)d_in[4];
    const float* ar0    = (const float*)d_in[5];
    const float* W1     = (const float*)d_in[6];
    const float* al1    = (const float*)d_in[7];
    const float* ar1    = (const float*)d_in[8];
    const float* Wout   = (const float*)d_in[9];
    const float* bout   = (const float*)d_in[10];
    const int*   src    = (const int*)d_in[11];
    const int*   dst    = (const int*)d_in[12];

    float* out = (float*)d_out;
    float* outh = out;                          // [N,128]
    float* outlog = out + (size_t)GN * 128;     // [N,40]

    const int NP = 2 * GN;                      // batched paths
    // workspace layout
    ushort_t* featb = (ushort_t*)d_ws;                 // [2N,128] bf16   25.6 MB
    float* t0 = (float*)(featb + (size_t)NP * 128);    // [2N,128] fp32   51.2 MB
    float* el = t0 + (size_t)NP * 128;                 // [2N,4]
    float* er = el + (size_t)NP * GH;                  // [2N,4]
    int* row_ptr  = (int*)(er + (size_t)NP * GH);      // N+1
    int* wpos     = row_ptr + (GN + 1);                // N
    int* csr_src  = wpos + GN;                         // E
    int* partials = csr_src + GE;                      // 256

    const int NPH = NP * GH;
    const int nb = (GN + 255) / 256;
    const int eb = (GE + 255) / 256;
    const int gblocks = (NP + 63) / 64;
    const int lrblocks = (NPH + 255) / 256;
    const int aggblocks = (NP + 3) / 4;

    // ---- CSR build ----
    hipMemsetAsync(wpos, 0, GN * sizeof(int), stream);
    k_hist<<<eb, 256, 0, stream>>>(dst, wpos, GE);
    k_scan1<<<nb, 256, 0, stream>>>(wpos, row_ptr, partials, GN);
    k_scan2<<<1, 256, 0, stream>>>(partials, nb);
    k_scan3<<<nb, 256, 0, stream>>>(row_ptr, wpos, partials, GN, GE);
    k_fill<<<eb, 256, 0, stream>>>(src, dst, wpos, csr_src, GE);

    // ---- layer 1 (both paths batched as 2N rows) ----
    gemm_nk128<<<gblocks, 256, 0, stream>>>(inputs, target, W0, featb, NP);
    compute_lr<<<lrblocks, 256, 0, stream>>>(featb, al0, ar0, el, er, NPH);
    gat_agg<<<aggblocks, 256, 0, stream>>>(featb, el, er, row_ptr, csr_src,
                                           t0, 0, NP);

    // ---- layer 2 (residual in-place in t0) ----
    gemm_nk128<<<gblocks, 256, 0, stream>>>(t0, t0 + (size_t)GN * 128, W1, featb, NP);
    compute_lr<<<lrblocks, 256, 0, stream>>>(featb, al1, ar1, el, er, NPH);
    gat_agg<<<aggblocks, 256, 0, stream>>>(featb, el, er, row_ptr, csr_src,
                                           t0, 1, NP);

    // ---- mixup + projection ----
    out_mix<<<(GN + 3) / 4, 256, 0, stream>>>(t0, Wout, bout, lamb, outh, outlog, GN);
}

// Round 3
// 526.490 us; speedup vs baseline: 2.1789x; 1.0812x over previous
//
#include <hip/hip_runtime.h>
#include <hip/hip_bf16.h>
#include <cstddef>

#define GN 50000
#define GE 800000
#define GH 4
#define GD 32
#define SLOPE 0.2f

typedef unsigned short ushort_t;
typedef unsigned int uint_t;
using short8 = __attribute__((ext_vector_type(8))) short;
using float4v = __attribute__((ext_vector_type(4))) float;

__device__ __forceinline__ ushort_t f2bf(float f) {
    union { float f; uint_t u; } v; v.f = f;
    uint_t r = v.u + 0x7fff + ((v.u >> 16) & 1);   // RNE
    return (ushort_t)(r >> 16);
}

// ---------------- CSR build ----------------
__global__ void k_hist(const int* __restrict__ dst, int* __restrict__ deg, int E) {
    int i = blockIdx.x * 256 + threadIdx.x;
    if (i < E) atomicAdd(&deg[dst[i]], 1);
}

__global__ void k_scan1(const int* __restrict__ deg, int* __restrict__ row_ptr,
                        int* __restrict__ partials, int n) {
    __shared__ int s[256];
    int t = threadIdx.x;
    int i = blockIdx.x * 256 + t;
    int v = (i < n) ? deg[i] : 0;
    s[t] = v;
    __syncthreads();
    for (int off = 1; off < 256; off <<= 1) {
        int add = (t >= off) ? s[t - off] : 0;
        __syncthreads();
        s[t] += add;
        __syncthreads();
    }
    if (i < n) row_ptr[i] = s[t] - v;
    if (t == 255) partials[blockIdx.x] = s[255];
}

__global__ void k_scan2(int* __restrict__ partials, int nb) {
    __shared__ int s[256];
    int t = threadIdx.x;
    int v = (t < nb) ? partials[t] : 0;
    s[t] = v;
    __syncthreads();
    for (int off = 1; off < 256; off <<= 1) {
        int add = (t >= off) ? s[t - off] : 0;
        __syncthreads();
        s[t] += add;
        __syncthreads();
    }
    if (t < nb) partials[t] = s[t] - v;
}

__global__ void k_scan3(int* __restrict__ row_ptr, int* __restrict__ wpos,
                        const int* __restrict__ partials, int n, int E) {
    int i = blockIdx.x * 256 + threadIdx.x;
    if (i < n) {
        int rp = row_ptr[i] + partials[i >> 8];
        row_ptr[i] = rp;
        wpos[i] = rp;
        if (i == 0) row_ptr[n] = E;
    }
}

__global__ void k_fill(const int* __restrict__ src, const int* __restrict__ dst,
                       int* __restrict__ wpos, int* __restrict__ csr_src,
                       int* __restrict__ csr_dst, int E) {
    int i = blockIdx.x * 256 + threadIdx.x;
    if (i < E) {
        int d = dst[i];
        int p = atomicAdd(&wpos[d], 1);
        csr_src[p] = src[i];
        csr_dst[p] = d;
    }
}

// ---------------- weight converts ----------------
// wbt[m][n][k] = W_m[k][n] as bf16 (m=0: W0, m=1: W1)
__global__ void k_cvt_w(const float* __restrict__ W0, const float* __restrict__ W1,
                        ushort_t* __restrict__ wbt) {
    int t = blockIdx.x * 256 + threadIdx.x;   // 0..32767
    int m = t >> 14;
    int o = t & 16383;
    int n = o >> 7, k = o & 127;
    const float* W = m ? W1 : W0;
    wbt[t] = f2bf(W[k * 128 + n]);
}

// inputs/target fp32 -> bf16 [2N,128]
__global__ void k_cvt_a(const float* __restrict__ A0, const float* __restrict__ A1,
                        ushort_t* __restrict__ out, int total4) {
    int i = blockIdx.x * 256 + threadIdx.x;
    if (i >= total4) return;
    size_t e = (size_t)i * 4;
    const float* srcp = (e < (size_t)GN * 128) ? (A0 + e) : (A1 + (e - (size_t)GN * 128));
    float4 v = *(const float4*)srcp;
    ushort4 o;
    o.x = f2bf(v.x); o.y = f2bf(v.y); o.z = f2bf(v.z); o.w = f2bf(v.w);
    *(ushort4*)&out[e] = o;
}

// ---------------- MFMA GEMM: Cb[M,128](bf16) = A[M,128](bf16) @ W ----------------
// WbT[n][k] = W[k][n], staged in LDS with +8 short row pad (bank-conflict-free)
__global__ __launch_bounds__(256) void gemm_mfma(const ushort_t* __restrict__ A,
                                                 const ushort_t* __restrict__ WbT,
                                                 ushort_t* __restrict__ Cb, int M) {
    __shared__ ushort_t Bs[128][136];
    int tid = threadIdx.x;
    for (int i = tid; i < 128 * 16; i += 256) {
        int n = i >> 4;
        int kc = (i & 15) << 3;
        short8 v = *(const short8*)&WbT[n * 128 + kc];
        *(short8*)&Bs[n][kc] = v;
    }
    __syncthreads();
    int wid = tid >> 6, lane = tid & 63;
    int r0 = blockIdx.x * 64 + wid * 16;
    int col = lane & 15, quad = lane >> 4;
    float4v acc[8];
#pragma unroll
    for (int t = 0; t < 8; t++) acc[t] = (float4v){0.f, 0.f, 0.f, 0.f};
    int arow = r0 + col;
    bool rowok = arow < M;
#pragma unroll
    for (int ks = 0; ks < 4; ks++) {
        short8 af = {};
        if (rowok) af = *(const short8*)&A[(size_t)arow * 128 + ks * 32 + quad * 8];
#pragma unroll
        for (int nt = 0; nt < 8; nt++) {
            short8 bf = *(const short8*)&Bs[nt * 16 + col][ks * 32 + quad * 8];
            acc[nt] = __builtin_amdgcn_mfma_f32_16x16x32_bf16(af, bf, acc[nt], 0, 0, 0);
        }
    }
#pragma unroll
    for (int nt = 0; nt < 8; nt++) {
#pragma unroll
        for (int r = 0; r < 4; r++) {
            int row = r0 + quad * 4 + r;
            if (row < M) Cb[(size_t)row * 128 + nt * 16 + col] = f2bf(acc[nt][r]);
        }
    }
}

// ---------------- attention logits el/er (bf16 feat) ----------------
__global__ void compute_lr(const ushort_t* __restrict__ featb,
                           const float* __restrict__ al, const float* __restrict__ ar,
                           float* __restrict__ el, float* __restrict__ er, int NPH) {
    int i = blockIdx.x * 256 + threadIdx.x;   // i = p*H + h
    if (i >= NPH) return;
    int h = i & (GH - 1);
    const uint_t* f = (const uint_t*)(featb + (size_t)(i >> 2) * 128 + h * GD);
    const float* a = al + h * GD;
    const float* b = ar + h * GD;
    float sl = 0.f, sr = 0.f;
#pragma unroll
    for (int q = 0; q < 16; q++) {
        uint_t u = f[q];
        float x = __uint_as_float(u << 16);
        float y = __uint_as_float(u & 0xffff0000u);
        sl += x * a[2 * q] + y * a[2 * q + 1];
        sr += x * b[2 * q] + y * b[2 * q + 1];
    }
    el[i] = sl;
    er[i] = sr;
}

// ---------------- per-edge softmax weights (both paths), CSR order ----------------
// aw[path][j][h] = exp(leaky(el[src_j]+er[dst_j])); no max-sub needed (|e| small)
__global__ void k_weights(const int* __restrict__ csr_src, const int* __restrict__ csr_dst,
                          const float* __restrict__ el, const float* __restrict__ er,
                          float* __restrict__ aw, int E4) {
    int t = blockIdx.x * 256 + threadIdx.x;
    if (t >= E4) return;
    int j = t >> 2, h = t & 3;
    int s = csr_src[j], d = csr_dst[j];
    float e0 = el[s * 4 + h] + er[d * 4 + h];
    e0 = e0 > 0.f ? e0 : SLOPE * e0;
    float e1 = el[(s + GN) * 4 + h] + er[(d + GN) * 4 + h];
    e1 = e1 > 0.f ? e1 : SLOPE * e1;
    aw[t] = __expf(e0);
    aw[E4 + t] = __expf(e1);
}

// ---------------- aggregate: gather + weighted sum (slim loop) ----------------
// one 64-lane wave per (node,path); lane owns dims 2l,2l+1; head=lane>>4
__global__ __launch_bounds__(256) void gat_agg2(
    const ushort_t* __restrict__ featb, const float* __restrict__ aw,
    const int* __restrict__ row_ptr, const int* __restrict__ csr_src,
    float* __restrict__ io, ushort_t* __restrict__ iob, int use_resid, int NP) {
    int p = blockIdx.x * 4 + (threadIdx.x >> 6);
    if (p >= NP) return;
    int lane = threadIdx.x & 63;
    int hh = lane >> 4;
    int n = (p < GN) ? p : p - GN;
    const ushort_t* fb = featb + ((p < GN) ? 0 : (size_t)GN * 128);
    const float* awp = aw + ((p < GN) ? 0 : (size_t)GE * 4);
    int base = row_ptr[n];
    int deg = row_ptr[n + 1] - base;
    int l2 = lane << 1;

    float acc0 = 0.f, acc1 = 0.f, ssum = 0.f;
    int i = 0;
    for (; i + 8 <= deg; i += 8) {
        int j = base + i;
        int s0 = csr_src[j + 0], s1 = csr_src[j + 1], s2 = csr_src[j + 2], s3 = csr_src[j + 3];
        int s4 = csr_src[j + 4], s5 = csr_src[j + 5], s6 = csr_src[j + 6], s7 = csr_src[j + 7];
        float w0 = awp[(j + 0) * 4 + hh], w1 = awp[(j + 1) * 4 + hh];
        float w2 = awp[(j + 2) * 4 + hh], w3 = awp[(j + 3) * 4 + hh];
        float w4 = awp[(j + 4) * 4 + hh], w5 = awp[(j + 5) * 4 + hh];
        float w6 = awp[(j + 6) * 4 + hh], w7 = awp[(j + 7) * 4 + hh];
        uint_t f0 = *(const uint_t*)&fb[(size_t)s0 * 128 + l2];
        uint_t f1 = *(const uint_t*)&fb[(size_t)s1 * 128 + l2];
        uint_t f2 = *(const uint_t*)&fb[(size_t)s2 * 128 + l2];
        uint_t f3 = *(const uint_t*)&fb[(size_t)s3 * 128 + l2];
        uint_t f4 = *(const uint_t*)&fb[(size_t)s4 * 128 + l2];
        uint_t f5 = *(const uint_t*)&fb[(size_t)s5 * 128 + l2];
        uint_t f6 = *(const uint_t*)&fb[(size_t)s6 * 128 + l2];
        uint_t f7 = *(const uint_t*)&fb[(size_t)s7 * 128 + l2];
        ssum += ((w0 + w1) + (w2 + w3)) + ((w4 + w5) + (w6 + w7));
        acc0 += w0 * __uint_as_float(f0 << 16) + w1 * __uint_as_float(f1 << 16) +
                w2 * __uint_as_float(f2 << 16) + w3 * __uint_as_float(f3 << 16) +
                w4 * __uint_as_float(f4 << 16) + w5 * __uint_as_float(f5 << 16) +
                w6 * __uint_as_float(f6 << 16) + w7 * __uint_as_float(f7 << 16);
        acc1 += w0 * __uint_as_float(f0 & 0xffff0000u) + w1 * __uint_as_float(f1 & 0xffff0000u) +
                w2 * __uint_as_float(f2 & 0xffff0000u) + w3 * __uint_as_float(f3 & 0xffff0000u) +
                w4 * __uint_as_float(f4 & 0xffff0000u) + w5 * __uint_as_float(f5 & 0xffff0000u) +
                w6 * __uint_as_float(f6 & 0xffff0000u) + w7 * __uint_as_float(f7 & 0xffff0000u);
    }
    for (; i < deg; i++) {
        int j = base + i;
        int s = csr_src[j];
        float w = awp[j * 4 + hh];
        uint_t f = *(const uint_t*)&fb[(size_t)s * 128 + l2];
        ssum += w;
        acc0 += w * __uint_as_float(f << 16);
        acc1 += w * __uint_as_float(f & 0xffff0000u);
    }
    float inv = (deg > 0) ? 1.f / ssum : 0.f;
    float v0 = acc0 * inv, v1 = acc1 * inv;
    size_t idx = (size_t)p * 128 + l2;
    if (use_resid) {
        float2 r = *(const float2*)&io[idx];
        v0 += r.x;
        v1 += r.y;
    }
    v0 = v0 > 0.f ? v0 : __expf(v0) - 1.f;
    v1 = v1 > 0.f ? v1 : __expf(v1) - 1.f;
    *(float2*)&io[idx] = make_float2(v0, v1);
    if (iob) {
        ushort2 ob;
        ob.x = f2bf(v0);
        ob.y = f2bf(v1);
        *(ushort2*)&iob[idx] = ob;
    }
}

// ---------------- mixup + output projection ----------------
__global__ __launch_bounds__(256) void out_mix(const float* __restrict__ hbuf,
                                               const float* __restrict__ Wout,
                                               const float* __restrict__ bout,
                                               const float* __restrict__ lamb,
                                               float* __restrict__ outh,
                                               float* __restrict__ outlog, int Nn) {
    __shared__ float hs[4][128];
    int w = threadIdx.x >> 6;
    int node = blockIdx.x * 4 + w;
    int lane = threadIdx.x & 63;
    float lam = lamb[0];
    if (node < Nn) {
        size_t i1 = (size_t)node * 128 + (lane << 1);
        size_t i2 = (size_t)(node + GN) * 128 + (lane << 1);
        float2 a = *(const float2*)&hbuf[i1];
        float2 b = *(const float2*)&hbuf[i2];
        float m0 = lam * a.x + (1.f - lam) * b.x;
        float m1 = lam * a.y + (1.f - lam) * b.y;
        *(float2*)&outh[i1] = make_float2(m0, m1);
        hs[w][lane * 2] = m0;
        hs[w][lane * 2 + 1] = m1;
    }
    __syncthreads();
    if (node < Nn && lane < 40) {
        float acc = bout[lane];
#pragma unroll 4
        for (int k = 0; k < 128; k++) acc += hs[w][k] * Wout[k * 40 + lane];
        outlog[(size_t)node * 40 + lane] = acc;
    }
}

extern "C" void kernel_launch(void* const* d_in, const int* in_sizes, int n_in,
                              void* d_out, int out_size, void* d_ws, size_t ws_size,
                              hipStream_t stream) {
    const float* inputs = (const float*)d_in[0];
    const float* target = (const float*)d_in[1];
    const float* lamb   = (const float*)d_in[2];
    const float* W0     = (const float*)d_in[3];
    const float* al0    = (const float*)d_in[4];
    const float* ar0    = (const float*)d_in[5];
    const float* W1     = (const float*)d_in[6];
    const float* al1    = (const float*)d_in[7];
    const float* ar1    = (const float*)d_in[8];
    const float* Wout   = (const float*)d_in[9];
    const float* bout   = (const float*)d_in[10];
    const int*   src    = (const int*)d_in[11];
    const int*   dst    = (const int*)d_in[12];

    float* out = (float*)d_out;
    float* outh = out;                          // [N,128]
    float* outlog = out + (size_t)GN * 128;     // [N,40]

    const int NP = 2 * GN;
    const int E4 = GE * 4;
    // workspace layout (~137 MB)
    ushort_t* featb = (ushort_t*)d_ws;                    // [2N,128] bf16
    ushort_t* abuf  = featb + (size_t)NP * 128;           // [2N,128] bf16 (Ab, then t0b)
    float* t0 = (float*)(abuf + (size_t)NP * 128);        // [2N,128] fp32
    float* el = t0 + (size_t)NP * 128;                    // [2N,4]
    float* er = el + (size_t)NP * GH;                     // [2N,4]
    float* aw = er + (size_t)NP * GH;                     // [2][E][4] fp32
    ushort_t* wbt = (ushort_t*)(aw + (size_t)2 * E4);     // [2][128][128] bf16
    int* row_ptr  = (int*)(wbt + 2 * 128 * 128);          // N+1
    int* wpos     = row_ptr + (GN + 1);                   // N
    int* csr_src  = wpos + GN;                            // E
    int* csr_dst  = csr_src + GE;                         // E
    int* partials = csr_dst + GE;                         // 256

    const int NPH = NP * GH;
    const int nb = (GN + 255) / 256;
    const int eb = (GE + 255) / 256;
    const int gblocks = (NP + 63) / 64;
    const int lrblocks = (NPH + 255) / 256;
    const int aggblocks = (NP + 3) / 4;
    const int wblocks = (E4 + 255) / 256;
    const int cvtblocks = (NP * 32 + 255) / 256;

    // ---- CSR build ----
    hipMemsetAsync(wpos, 0, GN * sizeof(int), stream);
    k_hist<<<eb, 256, 0, stream>>>(dst, wpos, GE);
    k_scan1<<<nb, 256, 0, stream>>>(wpos, row_ptr, partials, GN);
    k_scan2<<<1, 256, 0, stream>>>(partials, nb);
    k_scan3<<<nb, 256, 0, stream>>>(row_ptr, wpos, partials, GN, GE);
    k_fill<<<eb, 256, 0, stream>>>(src, dst, wpos, csr_src, csr_dst, GE);

    // ---- converts ----
    k_cvt_w<<<128, 256, 0, stream>>>(W0, W1, wbt);
    k_cvt_a<<<cvtblocks, 256, 0, stream>>>(inputs, target, abuf, NP * 32);

    // ---- layer 1 ----
    gemm_mfma<<<gblocks, 256, 0, stream>>>(abuf, wbt, featb, NP);
    compute_lr<<<lrblocks, 256, 0, stream>>>(featb, al0, ar0, el, er, NPH);
    k_weights<<<wblocks, 256, 0, stream>>>(csr_src, csr_dst, el, er, aw, E4);
    gat_agg2<<<aggblocks, 256, 0, stream>>>(featb, aw, row_ptr, csr_src,
                                            t0, abuf, 0, NP);

    // ---- layer 2 ----
    gemm_mfma<<<gblocks, 256, 0, stream>>>(abuf, wbt + 128 * 128, featb, NP);
    compute_lr<<<lrblocks, 256, 0, stream>>>(featb, al1, ar1, el, er, NPH);
    k_weights<<<wblocks, 256, 0, stream>>>(csr_src, csr_dst, el, er, aw, E4);
    gat_agg2<<<aggblocks, 256, 0, stream>>>(featb, aw, row_ptr, csr_src,
                                            t0, nullptr, 1, NP);

    // ---- mixup + projection ----
    out_mix<<<(GN + 3) / 4, 256, 0, stream>>>(t0, Wout, bout, lamb, outh, outlog, GN);
}

// Round 4
// 495.233 us; speedup vs baseline: 2.3164x; 1.0631x over previous
//
#include <hip/hip_runtime.h>
#include <hip/hip_bf16.h>
#include <cstddef>

#define GN 50000
#define GE 800000
#define GH 4
#define GD 32
#define SLOPE 0.2f

typedef unsigned short ushort_t;
typedef unsigned int uint_t;
using short8 = __attribute__((ext_vector_type(8))) short;
using float4v = __attribute__((ext_vector_type(4))) float;

__device__ __forceinline__ ushort_t f2bf(float f) {
    union { float f; uint_t u; } v; v.f = f;
    uint_t r = v.u + 0x7fff + ((v.u >> 16) & 1);   // RNE
    return (ushort_t)(r >> 16);
}
__device__ __forceinline__ float bflo(uint_t u) { return __uint_as_float(u << 16); }
__device__ __forceinline__ float bfhi(uint_t u) { return __uint_as_float(u & 0xffff0000u); }

// ---------------- CSR build ----------------
__global__ void k_hist(const int* __restrict__ dst, int* __restrict__ deg, int E) {
    int i = blockIdx.x * 256 + threadIdx.x;
    if (i < E) atomicAdd(&deg[dst[i]], 1);
}

__global__ void k_scan1(const int* __restrict__ deg, int* __restrict__ row_ptr,
                        int* __restrict__ partials, int n) {
    __shared__ int s[256];
    int t = threadIdx.x;
    int i = blockIdx.x * 256 + t;
    int v = (i < n) ? deg[i] : 0;
    s[t] = v;
    __syncthreads();
    for (int off = 1; off < 256; off <<= 1) {
        int add = (t >= off) ? s[t - off] : 0;
        __syncthreads();
        s[t] += add;
        __syncthreads();
    }
    if (i < n) row_ptr[i] = s[t] - v;
    if (t == 255) partials[blockIdx.x] = s[255];
}

__global__ void k_scan2(int* __restrict__ partials, int nb) {
    __shared__ int s[256];
    int t = threadIdx.x;
    int v = (t < nb) ? partials[t] : 0;
    s[t] = v;
    __syncthreads();
    for (int off = 1; off < 256; off <<= 1) {
        int add = (t >= off) ? s[t - off] : 0;
        __syncthreads();
        s[t] += add;
        __syncthreads();
    }
    if (t < nb) partials[t] = s[t] - v;
}

__global__ void k_scan3(int* __restrict__ row_ptr, int* __restrict__ wpos,
                        const int* __restrict__ partials, int n, int E) {
    int i = blockIdx.x * 256 + threadIdx.x;
    if (i < n) {
        int rp = row_ptr[i] + partials[i >> 8];
        row_ptr[i] = rp;
        wpos[i] = rp;
        if (i == 0) row_ptr[n] = E;
    }
}

__global__ void k_fill(const int* __restrict__ src, const int* __restrict__ dst,
                       int* __restrict__ wpos, int2* __restrict__ csr_sd, int E) {
    int i = blockIdx.x * 256 + threadIdx.x;
    if (i < E) {
        int d = dst[i];
        int p = atomicAdd(&wpos[d], 1);
        csr_sd[p] = make_int2(src[i], d);
    }
}

// ---------------- weight transpose+convert ----------------
__global__ void k_cvt_w(const float* __restrict__ W0, const float* __restrict__ W1,
                        ushort_t* __restrict__ wbt) {
    int t = blockIdx.x * 256 + threadIdx.x;   // 0..32767
    int m = t >> 14;
    int o = t & 16383;
    int n = o >> 7, k = o & 127;
    const float* W = m ? W1 : W0;
    wbt[t] = f2bf(W[k * 128 + n]);
}

// ---------------- MFMA GEMM (fp32 A, layer 1): Cb = [A0;A1] @ W ----------------
__global__ __launch_bounds__(256) void gemm_mfma32(const float* __restrict__ A0,
                                                   const float* __restrict__ A1,
                                                   const ushort_t* __restrict__ WbT,
                                                   ushort_t* __restrict__ Cb, int M) {
    __shared__ ushort_t Bs[128][136];
    int tid = threadIdx.x;
    for (int i = tid; i < 128 * 16; i += 256) {
        int n = i >> 4;
        int kc = (i & 15) << 3;
        *(short8*)&Bs[n][kc] = *(const short8*)&WbT[n * 128 + kc];
    }
    __syncthreads();
    int wid = tid >> 6, lane = tid & 63;
    int r0 = blockIdx.x * 64 + wid * 16;
    int col = lane & 15, quad = lane >> 4;
    float4v acc[8];
#pragma unroll
    for (int t = 0; t < 8; t++) acc[t] = (float4v){0.f, 0.f, 0.f, 0.f};
    int arow = r0 + col;
    bool rowok = arow < M;
    const float* Ar = nullptr;
    if (rowok) Ar = (arow < GN) ? (A0 + (size_t)arow * 128)
                                : (A1 + (size_t)(arow - GN) * 128);
#pragma unroll
    for (int ks = 0; ks < 4; ks++) {
        short8 af = {};
        if (rowok) {
            float4 v0 = *(const float4*)&Ar[ks * 32 + quad * 8];
            float4 v1 = *(const float4*)&Ar[ks * 32 + quad * 8 + 4];
            af[0] = (short)f2bf(v0.x); af[1] = (short)f2bf(v0.y);
            af[2] = (short)f2bf(v0.z); af[3] = (short)f2bf(v0.w);
            af[4] = (short)f2bf(v1.x); af[5] = (short)f2bf(v1.y);
            af[6] = (short)f2bf(v1.z); af[7] = (short)f2bf(v1.w);
        }
#pragma unroll
        for (int nt = 0; nt < 8; nt++) {
            short8 bf = *(const short8*)&Bs[nt * 16 + col][ks * 32 + quad * 8];
            acc[nt] = __builtin_amdgcn_mfma_f32_16x16x32_bf16(af, bf, acc[nt], 0, 0, 0);
        }
    }
#pragma unroll
    for (int nt = 0; nt < 8; nt++) {
#pragma unroll
        for (int r = 0; r < 4; r++) {
            int row = r0 + quad * 4 + r;
            if (row < M) Cb[(size_t)row * 128 + nt * 16 + col] = f2bf(acc[nt][r]);
        }
    }
}

// ---------------- MFMA GEMM (bf16 A, layer 2) ----------------
__global__ __launch_bounds__(256) void gemm_mfma(const ushort_t* __restrict__ A,
                                                 const ushort_t* __restrict__ WbT,
                                                 ushort_t* __restrict__ Cb, int M) {
    __shared__ ushort_t Bs[128][136];
    int tid = threadIdx.x;
    for (int i = tid; i < 128 * 16; i += 256) {
        int n = i >> 4;
        int kc = (i & 15) << 3;
        *(short8*)&Bs[n][kc] = *(const short8*)&WbT[n * 128 + kc];
    }
    __syncthreads();
    int wid = tid >> 6, lane = tid & 63;
    int r0 = blockIdx.x * 64 + wid * 16;
    int col = lane & 15, quad = lane >> 4;
    float4v acc[8];
#pragma unroll
    for (int t = 0; t < 8; t++) acc[t] = (float4v){0.f, 0.f, 0.f, 0.f};
    int arow = r0 + col;
    bool rowok = arow < M;
#pragma unroll
    for (int ks = 0; ks < 4; ks++) {
        short8 af = {};
        if (rowok) af = *(const short8*)&A[(size_t)arow * 128 + ks * 32 + quad * 8];
#pragma unroll
        for (int nt = 0; nt < 8; nt++) {
            short8 bf = *(const short8*)&Bs[nt * 16 + col][ks * 32 + quad * 8];
            acc[nt] = __builtin_amdgcn_mfma_f32_16x16x32_bf16(af, bf, acc[nt], 0, 0, 0);
        }
    }
#pragma unroll
    for (int nt = 0; nt < 8; nt++) {
#pragma unroll
        for (int r = 0; r < 4; r++) {
            int row = r0 + quad * 4 + r;
            if (row < M) Cb[(size_t)row * 128 + nt * 16 + col] = f2bf(acc[nt][r]);
        }
    }
}

// ---------------- attention logits el/er (bf16 feat) ----------------
__global__ void compute_lr(const ushort_t* __restrict__ featb,
                           const float* __restrict__ al, const float* __restrict__ ar,
                           float* __restrict__ el, float* __restrict__ er, int NPH) {
    int i = blockIdx.x * 256 + threadIdx.x;   // i = p*H + h
    if (i >= NPH) return;
    int h = i & (GH - 1);
    const uint_t* f = (const uint_t*)(featb + (size_t)(i >> 2) * 128 + h * GD);
    const float* a = al + h * GD;
    const float* b = ar + h * GD;
    float sl = 0.f, sr = 0.f;
#pragma unroll
    for (int q = 0; q < 16; q++) {
        uint_t u = f[q];
        float x = bflo(u), y = bfhi(u);
        sl += x * a[2 * q] + y * a[2 * q + 1];
        sr += x * b[2 * q] + y * b[2 * q + 1];
    }
    el[i] = sl;
    er[i] = sr;
}

// ---------------- per-edge softmax weights, both paths packed bf16x2 ----------------
__global__ void k_weights(const int2* __restrict__ csr_sd,
                          const float* __restrict__ el, const float* __restrict__ er,
                          uint_t* __restrict__ aw, int E4) {
    int t = blockIdx.x * 256 + threadIdx.x;
    if (t >= E4) return;
    int j = t >> 2, h = t & 3;
    int2 sd = csr_sd[j];
    float e0 = el[sd.x * 4 + h] + er[sd.y * 4 + h];
    e0 = e0 > 0.f ? e0 : SLOPE * e0;
    float e1 = el[(sd.x + GN) * 4 + h] + er[(sd.y + GN) * 4 + h];
    e1 = e1 > 0.f ? e1 : SLOPE * e1;
    aw[t] = ((uint_t)f2bf(__expf(e1)) << 16) | (uint_t)f2bf(__expf(e0));
}

// ---------------- aggregate: one wave per node, BOTH paths ----------------
// lane owns dims 2l,2l+1; head = lane>>4
__global__ __launch_bounds__(256) void gat_agg3(
    const ushort_t* __restrict__ featb, const uint_t* __restrict__ aw,
    const int* __restrict__ row_ptr, const int2* __restrict__ csr_sd,
    float* __restrict__ io, ushort_t* __restrict__ iob, int use_resid) {
    int n = blockIdx.x * 4 + (threadIdx.x >> 6);
    if (n >= GN) return;
    int lane = threadIdx.x & 63;
    int hh = lane >> 4;
    int l2 = lane << 1;
    int base = row_ptr[n];
    int deg = row_ptr[n + 1] - base;
    const ushort_t* fb1 = featb + (size_t)GN * 128;

    float a00 = 0.f, a01 = 0.f, a10 = 0.f, a11 = 0.f, ss0 = 0.f, ss1 = 0.f;
    int i = 0;
    for (; i + 8 <= deg; i += 8) {
        int j = base + i;
        int s0 = csr_sd[j + 0].x, s1 = csr_sd[j + 1].x, s2 = csr_sd[j + 2].x, s3 = csr_sd[j + 3].x;
        int s4 = csr_sd[j + 4].x, s5 = csr_sd[j + 5].x, s6 = csr_sd[j + 6].x, s7 = csr_sd[j + 7].x;
        uint_t p0 = aw[(j + 0) * 4 + hh], p1 = aw[(j + 1) * 4 + hh];
        uint_t p2 = aw[(j + 2) * 4 + hh], p3 = aw[(j + 3) * 4 + hh];
        uint_t p4 = aw[(j + 4) * 4 + hh], p5 = aw[(j + 5) * 4 + hh];
        uint_t p6 = aw[(j + 6) * 4 + hh], p7 = aw[(j + 7) * 4 + hh];
        uint_t f0 = *(const uint_t*)&featb[(size_t)s0 * 128 + l2];
        uint_t f1 = *(const uint_t*)&featb[(size_t)s1 * 128 + l2];
        uint_t f2 = *(const uint_t*)&featb[(size_t)s2 * 128 + l2];
        uint_t f3 = *(const uint_t*)&featb[(size_t)s3 * 128 + l2];
        uint_t f4 = *(const uint_t*)&featb[(size_t)s4 * 128 + l2];
        uint_t f5 = *(const uint_t*)&featb[(size_t)s5 * 128 + l2];
        uint_t f6 = *(const uint_t*)&featb[(size_t)s6 * 128 + l2];
        uint_t f7 = *(const uint_t*)&featb[(size_t)s7 * 128 + l2];
        uint_t g0 = *(const uint_t*)&fb1[(size_t)s0 * 128 + l2];
        uint_t g1 = *(const uint_t*)&fb1[(size_t)s1 * 128 + l2];
        uint_t g2 = *(const uint_t*)&fb1[(size_t)s2 * 128 + l2];
        uint_t g3 = *(const uint_t*)&fb1[(size_t)s3 * 128 + l2];
        uint_t g4 = *(const uint_t*)&fb1[(size_t)s4 * 128 + l2];
        uint_t g5 = *(const uint_t*)&fb1[(size_t)s5 * 128 + l2];
        uint_t g6 = *(const uint_t*)&fb1[(size_t)s6 * 128 + l2];
        uint_t g7 = *(const uint_t*)&fb1[(size_t)s7 * 128 + l2];
        float w00 = bflo(p0), w01 = bflo(p1), w02 = bflo(p2), w03 = bflo(p3);
        float w04 = bflo(p4), w05 = bflo(p5), w06 = bflo(p6), w07 = bflo(p7);
        float w10 = bfhi(p0), w11 = bfhi(p1), w12 = bfhi(p2), w13 = bfhi(p3);
        float w14 = bfhi(p4), w15 = bfhi(p5), w16 = bfhi(p6), w17 = bfhi(p7);
        ss0 += ((w00 + w01) + (w02 + w03)) + ((w04 + w05) + (w06 + w07));
        ss1 += ((w10 + w11) + (w12 + w13)) + ((w14 + w15) + (w16 + w17));
        a00 += w00 * bflo(f0) + w01 * bflo(f1) + w02 * bflo(f2) + w03 * bflo(f3) +
               w04 * bflo(f4) + w05 * bflo(f5) + w06 * bflo(f6) + w07 * bflo(f7);
        a01 += w00 * bfhi(f0) + w01 * bfhi(f1) + w02 * bfhi(f2) + w03 * bfhi(f3) +
               w04 * bfhi(f4) + w05 * bfhi(f5) + w06 * bfhi(f6) + w07 * bfhi(f7);
        a10 += w10 * bflo(g0) + w11 * bflo(g1) + w12 * bflo(g2) + w13 * bflo(g3) +
               w14 * bflo(g4) + w15 * bflo(g5) + w16 * bflo(g6) + w17 * bflo(g7);
        a11 += w10 * bfhi(g0) + w11 * bfhi(g1) + w12 * bfhi(g2) + w13 * bfhi(g3) +
               w14 * bfhi(g4) + w15 * bfhi(g5) + w16 * bfhi(g6) + w17 * bfhi(g7);
    }
    for (; i < deg; i++) {
        int j = base + i;
        int s = csr_sd[j].x;
        uint_t p = aw[j * 4 + hh];
        uint_t f = *(const uint_t*)&featb[(size_t)s * 128 + l2];
        uint_t g = *(const uint_t*)&fb1[(size_t)s * 128 + l2];
        float w0 = bflo(p), w1 = bfhi(p);
        ss0 += w0; ss1 += w1;
        a00 += w0 * bflo(f); a01 += w0 * bfhi(f);
        a10 += w1 * bflo(g); a11 += w1 * bfhi(g);
    }
    float inv0 = (deg > 0) ? 1.f / ss0 : 0.f;
    float inv1 = (deg > 0) ? 1.f / ss1 : 0.f;
    float v00 = a00 * inv0, v01 = a01 * inv0;
    float v10 = a10 * inv1, v11 = a11 * inv1;
    size_t idx0 = (size_t)n * 128 + l2;
    size_t idx1 = (size_t)(n + GN) * 128 + l2;
    if (use_resid) {
        float2 r0 = *(const float2*)&io[idx0];
        float2 r1 = *(const float2*)&io[idx1];
        v00 += r0.x; v01 += r0.y;
        v10 += r1.x; v11 += r1.y;
    }
    v00 = v00 > 0.f ? v00 : __expf(v00) - 1.f;
    v01 = v01 > 0.f ? v01 : __expf(v01) - 1.f;
    v10 = v10 > 0.f ? v10 : __expf(v10) - 1.f;
    v11 = v11 > 0.f ? v11 : __expf(v11) - 1.f;
    *(float2*)&io[idx0] = make_float2(v00, v01);
    *(float2*)&io[idx1] = make_float2(v10, v11);
    if (iob) {
        ushort2 o0; o0.x = f2bf(v00); o0.y = f2bf(v01);
        ushort2 o1; o1.x = f2bf(v10); o1.y = f2bf(v11);
        *(ushort2*)&iob[idx0] = o0;
        *(ushort2*)&iob[idx1] = o1;
    }
}

// ---------------- mixup + output projection ----------------
__global__ __launch_bounds__(256) void out_mix(const float* __restrict__ hbuf,
                                               const float* __restrict__ Wout,
                                               const float* __restrict__ bout,
                                               const float* __restrict__ lamb,
                                               float* __restrict__ outh,
                                               float* __restrict__ outlog, int Nn) {
    __shared__ float hs[4][128];
    int w = threadIdx.x >> 6;
    int node = blockIdx.x * 4 + w;
    int lane = threadIdx.x & 63;
    float lam = lamb[0];
    if (node < Nn) {
        size_t i1 = (size_t)node * 128 + (lane << 1);
        size_t i2 = (size_t)(node + GN) * 128 + (lane << 1);
        float2 a = *(const float2*)&hbuf[i1];
        float2 b = *(const float2*)&hbuf[i2];
        float m0 = lam * a.x + (1.f - lam) * b.x;
        float m1 = lam * a.y + (1.f - lam) * b.y;
        *(float2*)&outh[i1] = make_float2(m0, m1);
        hs[w][lane * 2] = m0;
        hs[w][lane * 2 + 1] = m1;
    }
    __syncthreads();
    if (node < Nn && lane < 40) {
        float acc = bout[lane];
#pragma unroll 4
        for (int k = 0; k < 128; k++) acc += hs[w][k] * Wout[k * 40 + lane];
        outlog[(size_t)node * 40 + lane] = acc;
    }
}

extern "C" void kernel_launch(void* const* d_in, const int* in_sizes, int n_in,
                              void* d_out, int out_size, void* d_ws, size_t ws_size,
                              hipStream_t stream) {
    const float* inputs = (const float*)d_in[0];
    const float* target = (const float*)d_in[1];
    const float* lamb   = (const float*)d_in[2];
    const float* W0     = (const float*)d_in[3];
    const float* al0    = (const float*)d_in[4];
    const float* ar0    = (const float*)d_in[5];
    const float* W1     = (const float*)d_in[6];
    const float* al1    = (const float*)d_in[7];
    const float* ar1    = (const float*)d_in[8];
    const float* Wout   = (const float*)d_in[9];
    const float* bout   = (const float*)d_in[10];
    const int*   src    = (const int*)d_in[11];
    const int*   dst    = (const int*)d_in[12];

    float* out = (float*)d_out;
    float* outh = out;                          // [N,128]
    float* outlog = out + (size_t)GN * 128;     // [N,40]

    const int NP = 2 * GN;
    const int E4 = GE * 4;
    // workspace layout
    ushort_t* featb = (ushort_t*)d_ws;                    // [2N,128] bf16
    ushort_t* abuf  = featb + (size_t)NP * 128;           // [2N,128] bf16 (layer1 agg out)
    float* t0 = (float*)(abuf + (size_t)NP * 128);        // [2N,128] fp32
    float* el = t0 + (size_t)NP * 128;                    // [2N,4]
    float* er = el + (size_t)NP * GH;                     // [2N,4]
    uint_t* aw = (uint_t*)(er + (size_t)NP * GH);         // [E,4] bf16x2 packed
    ushort_t* wbt = (ushort_t*)(aw + (size_t)E4);         // [2][128][128] bf16
    int* row_ptr  = (int*)(wbt + 2 * 128 * 128);          // N+1
    int* wpos     = row_ptr + (GN + 1);                   // N
    int2* csr_sd  = (int2*)(wpos + GN);                   // E
    int* partials = (int*)(csr_sd + GE);                  // 256

    const int NPH = NP * GH;
    const int nb = (GN + 255) / 256;
    const int eb = (GE + 255) / 256;
    const int gblocks = (NP + 63) / 64;
    const int lrblocks = (NPH + 255) / 256;
    const int aggblocks = (GN + 3) / 4;
    const int wblocks = (E4 + 255) / 256;

    // ---- CSR build ----
    hipMemsetAsync(wpos, 0, GN * sizeof(int), stream);
    k_hist<<<eb, 256, 0, stream>>>(dst, wpos, GE);
    k_scan1<<<nb, 256, 0, stream>>>(wpos, row_ptr, partials, GN);
    k_scan2<<<1, 256, 0, stream>>>(partials, nb);
    k_scan3<<<nb, 256, 0, stream>>>(row_ptr, wpos, partials, GN, GE);
    k_fill<<<eb, 256, 0, stream>>>(src, dst, wpos, csr_sd, GE);

    // ---- weights convert ----
    k_cvt_w<<<128, 256, 0, stream>>>(W0, W1, wbt);

    // ---- layer 1 ----
    gemm_mfma32<<<gblocks, 256, 0, stream>>>(inputs, target, wbt, featb, NP);
    compute_lr<<<lrblocks, 256, 0, stream>>>(featb, al0, ar0, el, er, NPH);
    k_weights<<<wblocks, 256, 0, stream>>>(csr_sd, el, er, aw, E4);
    gat_agg3<<<aggblocks, 256, 0, stream>>>(featb, aw, row_ptr, csr_sd,
                                            t0, abuf, 0);

    // ---- layer 2 ----
    gemm_mfma<<<gblocks, 256, 0, stream>>>(abuf, wbt + 128 * 128, featb, NP);
    compute_lr<<<lrblocks, 256, 0, stream>>>(featb, al1, ar1, el, er, NPH);
    k_weights<<<wblocks, 256, 0, stream>>>(csr_sd, el, er, aw, E4);
    gat_agg3<<<aggblocks, 256, 0, stream>>>(featb, aw, row_ptr, csr_sd,
                                            t0, nullptr, 1);

    // ---- mixup + projection ----
    out_mix<<<(GN + 3) / 4, 256, 0, stream>>>(t0, Wout, bout, lamb, outh, outlog, GN);
}